// Round 18
// baseline (87.258 us; speedup 1.0000x reference)
//
#include <hip/hip_runtime.h>
#include <hip/hip_bf16.h>

typedef __bf16 bf16x8 __attribute__((ext_vector_type(8)));
typedef float  f32x4  __attribute__((ext_vector_type(4)));

// ---------------------------------------------------------------------------
// Stage 1: qkv = kern_tok @ qkv_w + qkv_b ; split into q(scaled),k,v
// ---------------------------------------------------------------------------
__global__ __launch_bounds__(192) void qkv_kernel(
    const float* __restrict__ conv_w, const float* __restrict__ qkv_w,
    const float* __restrict__ qkv_b,
    float* __restrict__ qv, float* __restrict__ kvv, float* __restrict__ vv)
{
    __shared__ float tok[64];
    const int bid = blockIdx.x;          // co*36 + s
    const int co = bid / 36, s = bid - co * 36;
    const int w = s / 9, p = s - w * 9;
    const int t = threadIdx.x;           // 192
    if (t < 64) tok[t] = conv_w[(((w * 64 + co) * 64 + t) * 9) + p];
    __syncthreads();
    float acc = qkv_b[t];
#pragma unroll 8
    for (int ci = 0; ci < 64; ++ci) acc += tok[ci] * qkv_w[ci * 192 + t];
    const int trip = t >> 6, rem = t & 63, h = rem >> 3, d = rem & 7;
    if (trip == 0) acc *= 0.35355339059327373f;   // hd^-0.5, hd=8
    float* dst = (trip == 0) ? qv : ((trip == 1) ? kvv : vv);
    dst[((co * 8 + h) * 36 + s) * 8 + d] = acc;
}

// ---------------------------------------------------------------------------
// Stage 2: attention per (co, head): softmax(q k^T) v  -> ao[co][s][h*8+d]
// ---------------------------------------------------------------------------
__global__ __launch_bounds__(64) void attn_kernel(
    const float* __restrict__ qv, const float* __restrict__ kvv,
    const float* __restrict__ vv, float* __restrict__ ao)
{
    __shared__ float kl[288], vl[288];
    const int bid = blockIdx.x;          // co*8 + h
    const int t = threadIdx.x;           // 64
    const float* kb = kvv + bid * 288;
    const float* vb = vv + bid * 288;
    for (int i = t; i < 288; i += 64) { kl[i] = kb[i]; vl[i] = vb[i]; }
    __syncthreads();
    if (t < 36) {
        float q[8];
        const float* qb = qv + bid * 288 + t * 8;
#pragma unroll
        for (int d = 0; d < 8; ++d) q[d] = qb[d];
        float sc[36];
        float mx = -1e30f;
#pragma unroll
        for (int u = 0; u < 36; ++u) {
            float a = 0.f;
#pragma unroll
            for (int d = 0; d < 8; ++d) a += q[d] * kl[u * 8 + d];
            sc[u] = a;
            mx = fmaxf(mx, a);
        }
        float sum = 0.f;
        float o[8] = {0.f,0.f,0.f,0.f,0.f,0.f,0.f,0.f};
#pragma unroll
        for (int u = 0; u < 36; ++u) {
            float e = expf(sc[u] - mx);
            sum += e;
#pragma unroll
            for (int d = 0; d < 8; ++d) o[d] += e * vl[u * 8 + d];
        }
        const float inv = 1.0f / sum;
        const int co = bid >> 3, h = bid & 7;
        float* dst = ao + (co * 36 + t) * 64 + h * 8;
#pragma unroll
        for (int d = 0; d < 8; ++d) dst[d] = o[d] * inv;
    }
}

// ---------------------------------------------------------------------------
// Stage 3: proj + SE + write bf16 kernels.
// kout layout: [(w*9+p)][co][ci64] -- 8 KB contiguous per TAP, so conv can
// stage one full tap (K=64) per pipeline stage (9 stages instead of 18).
// ---------------------------------------------------------------------------
__global__ __launch_bounds__(64) void proj_se_kernel(
    const float* __restrict__ ao, const float* __restrict__ proj_w,
    const float* __restrict__ proj_b,
    const float* __restrict__ se_w1, const float* __restrict__ se_b1,
    const float* __restrict__ se_w2, const float* __restrict__ se_b2,
    ushort* __restrict__ kout)
{
    __shared__ float al[9][64];
    __shared__ float pool[64];
    __shared__ float hb[4];
    const int bid = blockIdx.x;          // w*64 + co
    const int w = bid >> 6, co = bid & 63;
    const int t = threadIdx.x;           // 64 (= ci)
    for (int i = t; i < 576; i += 64) {
        int p = i >> 6, j = i & 63;
        al[p][j] = ao[(co * 36 + w * 9 + p) * 64 + j];
    }
    __syncthreads();
    float kv[9];
#pragma unroll
    for (int p = 0; p < 9; ++p) {
        float a = proj_b[t];
#pragma unroll 8
        for (int j = 0; j < 64; ++j) a += al[p][j] * proj_w[j * 64 + t];
        kv[p] = a;
    }
    float pl = 0.f;
#pragma unroll
    for (int p = 0; p < 9; ++p) pl += kv[p];
    pool[t] = pl * (1.0f / 9.0f);
    __syncthreads();
    if (t < 4) {
        float hh = se_b1[w * 4 + t];
#pragma unroll 8
        for (int c = 0; c < 64; ++c) hh += pool[c] * se_w1[(w * 4 + t) * 64 + c];
        hb[t] = fmaxf(hh, 0.0f);
    }
    __syncthreads();
    float z = se_b2[w * 64 + t];
#pragma unroll
    for (int d = 0; d < 4; ++d) z += hb[d] * se_w2[(w * 64 + t) * 4 + d];
    const float sg = 1.0f / (1.0f + expf(-z));
#pragma unroll
    for (int p = 0; p < 9; ++p) {
        __hip_bfloat16 hv = __float2bfloat16(kv[p] * sg);
        kout[((w * 9 + p) * 64 + co) * 64 + t] = *(const ushort*)&hv;
    }
}

// ---------------------------------------------------------------------------
// Stage 4: dynamic per-window 3x3 conv, implicit GEMM, bf16 MFMA.
//
// Round-18 = R13's verified pipeline with 9 K=64 stages (was 18 K=32).
// R17's accounting: per-CU per-stage pipe work ~1200 cyc but measured
// stage time ~4100 cyc -- 3x slack attributed to the 18 per-stage
// vmcnt+barrier alignment points. This round halves them (9 barriers,
// 32 MFMA each) at the cost of occupancy (kern triple-buffer 3x8 KB ->
// LDS 66048 B -> 2 blocks/CU, 8 waves). R14 proved upward occupancy
// insensitivity (12->16 null); this disambiguates alignment-tax vs
// TLP-dominated. Mechanics (all R13-derived):
//  - kern row = 128 B (ci64): read XOR (co&7)<<4, DMA source pre-swizzle
//    ((lane>>3)&7)<<4 (quarter-wave analysis: 2-way aliasing = free).
//  - 2 DMA loads/wave/stage; vmcnt(2) mid-loop (sets {s,s+1} = 4 loads
//    outstanding; set s retired <=> <=2), vmcnt(0) at s=8.
//  - issue set s+2 (s<7) into buf (s+2)%3 right after the barrier.
// Kill-switch: regression => final answer is R13/R17 (83.4 us, verified
// twice); WRITE_SIZE must stay 131072 KB.
// ---------------------------------------------------------------------------
__global__ __launch_bounds__(256, 2) void conv_kernel(
    const float* __restrict__ x, const ushort* __restrict__ kern,
    float* __restrict__ out)
{
    __shared__ alignas(16) ushort in_lds[18 * 18 * 64];   // 41472 B
    __shared__ alignas(16) ushort kn_lds[3 * 4096];       // 24576 B (3 x 8KB)

    const int tid = threadIdx.x;

    // ---- XCD-chunked bijective remap: XCD k processes nb in [k*256,(k+1)*256)
    const int bid = blockIdx.x;                 // 0..2047, xcd = bid & 7
    const int nb  = ((bid & 7) << 8) + (bid >> 3);
    const int bz  = nb >> 6;                    // (w*8+b), 4 per XCD
    const int rem = nb & 63;
    const int i0  = (rem >> 3) << 4;
    const int j0  = (rem & 7) << 4;
    const int w = bz >> 3, b = bz & 7;
    const int gi = w >> 1, gj = w & 1;

    const int wv   = tid >> 6;
    const int lane = tid & 63;
    const int l15  = lane & 15;
    const int hi4  = lane >> 4;        // 0..3

    // ---- async kern stage: tap p -> one 8 KB chunk at kern + (w*9+p)*8192.
    // Linear LDS dest; read-side swizzle (co&7)<<4 realized by pre-swizzling
    // the GLOBAL source: for dest offset o, (o>>7)&7 == (lane>>3)&7 for both
    // the +0 and +1024 loads (wv*2048 and 1024 are 0 mod 8 rows).
    const char* kern_b = (const char*)kern;
    const int ksrc8 = ((lane >> 3) & 7) << 4;
    auto stage_kern = [&](int p, int buf) {
        const char* gs = kern_b + ((size_t)(w * 9 + p) << 13);
        const int woA = (wv << 11) + (lane << 4);
        const int woB = woA + 1024;
        __builtin_amdgcn_global_load_lds(
            (const __attribute__((address_space(1))) unsigned int*)(gs + (woA ^ ksrc8)),
            (__attribute__((address_space(3))) unsigned int*)
                ((char*)kn_lds + (buf << 13) + woA),
            16, 0, 0);
        __builtin_amdgcn_global_load_lds(
            (const __attribute__((address_space(1))) unsigned int*)(gs + (woB ^ ksrc8)),
            (__attribute__((address_space(3))) unsigned int*)
                ((char*)kn_lds + (buf << 13) + woB),
            16, 0, 0);
    };

    // ---- prologue: issue kern taps 0,1 first (fly under the input staging
    // burst), then stage the FULL input tile, then ONE full drain.
    stage_kern(0, 0);
    stage_kern(1, 1);

    // input staging, FULL 64 channels: 18x18 px * 128 B, 16 thr/px (4 ch).
    // All 21 clamped loads issued before the cvt/write pass (deep flight).
    // LDS position: (pp<<7) + ((cc*2) ^ ((q&7)<<4))  [0-conflict swizzle]
    {
        const int cc = (tid & 15) << 2;    // channel 0..60
        const int p0 = tid >> 4;           // 0..15
        float4 v[21];
        unsigned okm = 0;
#pragma unroll
        for (int k = 0; k < 21; ++k) {
            const int pp = p0 + (k << 4);          // <= 335
            const int ppc = pp < 323 ? pp : 323;
            const int r = ppc / 18, q = ppc - r * 18;
            const int iy = i0 - 1 + r, jx = j0 - 1 + q;
            const bool ok = (pp < 324) & (iy >= 0) & (iy < 128) & (jx >= 0) & (jx < 128);
            const int iyc = iy < 0 ? 0 : (iy > 127 ? 127 : iy);
            const int jxc = jx < 0 ? 0 : (jx > 127 ? 127 : jx);
            const size_t xi = (((size_t)b << 16) +
                               (size_t)(gi * 128 + iyc) * 256 + (size_t)(gj * 128 + jxc)) * 64 + cc;
            v[k] = *(const float4*)(x + xi);
            okm |= (unsigned)ok << k;
        }
#pragma unroll
        for (int k = 0; k < 21; ++k) {
            const int pp = p0 + (k << 4);
            if (pp < 324) {
                const int r = pp / 18, q = pp - r * 18;
                float4 z = (okm >> k) & 1 ? v[k] : make_float4(0.f, 0.f, 0.f, 0.f);
                union { ushort4 u; ushort h4[4]; } tmp;
                __hip_bfloat16 b0 = __float2bfloat16(z.x); tmp.h4[0] = *(const ushort*)&b0;
                __hip_bfloat16 b1 = __float2bfloat16(z.y); tmp.h4[1] = *(const ushort*)&b1;
                __hip_bfloat16 b2 = __float2bfloat16(z.z); tmp.h4[2] = *(const ushort*)&b2;
                __hip_bfloat16 b3 = __float2bfloat16(z.w); tmp.h4[3] = *(const ushort*)&b3;
                *(ushort4*)((char*)in_lds +
                    ((pp << 7) + ((cc << 1) ^ ((q & 7) << 4)))) = tmp.u;
            }
        }
    }

    f32x4 acc[4][4];
#pragma unroll
    for (int mf = 0; mf < 4; ++mf)
#pragma unroll
        for (int nf = 0; nf < 4; ++nf)
            acc[mf][nf] = (f32x4){0.f, 0.f, 0.f, 0.f};

    __syncthreads();     // the ONE full drain: input ds_writes + kern taps 0,1

#pragma unroll
    for (int s = 0; s < 9; ++s) {
        // counted wait: tap-s's 2 loads retired when <=2 outstanding
        // ({s,s+1} = 4 loads at stage top). s=8: queue is {8} -> vmcnt(0).
        if (s < 8) asm volatile("s_waitcnt vmcnt(2)" ::: "memory");
        else       asm volatile("s_waitcnt vmcnt(0)" ::: "memory");
        __builtin_amdgcn_sched_barrier(0);
        __builtin_amdgcn_s_barrier();      // all waves' tap-s loads in LDS
        __builtin_amdgcn_sched_barrier(0);

        // issue tap s+2 into buf (s+2)%3 before compute: all waves past
        // this barrier => all finished compute(s-1) = last readers of it.
        if (s < 7) stage_kern(s + 2, (s + 2) % 3);

        const int buf = s % 3;
        const int kh = s / 3, kw = s - kh * 3;

        // kern fragments: co = nf*16+l15; ks = ci-half; 128 B rows,
        // read offset ((ks<<6)|(hi4<<4)) ^ ((co&7)<<4)  [2-way = free]
        bf16x8 Kf[4][2];
#pragma unroll
        for (int nf = 0; nf < 4; ++nf) {
            const int co = nf * 16 + l15;
#pragma unroll
            for (int ks = 0; ks < 2; ++ks)
                Kf[nf][ks] = *(const bf16x8*)((const char*)kn_lds +
                              ((buf << 13) + (co << 7) +
                               (((ks << 6) | (hi4 << 4)) ^ ((co & 7) << 4))));
        }

        const int q = l15 + kw;
        const int swz = (q & 7) << 4;
#pragma unroll
        for (int mf = 0; mf < 4; ++mf) {
            const int r = wv * 4 + mf + kh;
            const int rowbase = (r * 18 + q) << 7;
#pragma unroll
            for (int ks = 0; ks < 2; ++ks) {
                const int c2 = (ks << 6) | (hi4 << 4);
                bf16x8 Af = *(const bf16x8*)((const char*)in_lds +
                              (rowbase + (c2 ^ swz)));
#pragma unroll
                for (int nf = 0; nf < 4; ++nf)
                    acc[mf][nf] = __builtin_amdgcn_mfma_f32_16x16x32_bf16(
                        Kf[nf][ks], Af, acc[mf][nf], 0, 0, 0);
            }
        }
    }

    // ---- pre-epilogue barrier: my ds_reads retired (lgkm 0), then all
    // waves arrive => nobody still reads in_lds when we overwrite it.
    asm volatile("s_waitcnt lgkmcnt(0)" ::: "memory");
    __builtin_amdgcn_sched_barrier(0);
    __builtin_amdgcn_s_barrier();
    __builtin_amdgcn_sched_barrier(0);

    // ---- LDS-transpose epilogue (wave-private 4 KB region). Plain cached
    // stores, 1 KB contiguous per wave-instruction.
    char* ep = (char*)in_lds + (wv << 12);
#pragma unroll
    for (int mf = 0; mf < 4; ++mf) {
        const int iloc = wv * 4 + mf;
        const size_t rowoff = ((size_t)b << 16) +
                              (size_t)(gi * 128 + i0 + iloc) * 256 + (size_t)(gj * 128 + j0);
        // scatter: lane(l15,hi4) holds co = nf*16+hi4*4+reg at pixel l15
#pragma unroll
        for (int nf = 0; nf < 4; ++nf) {
            const int off = (nf * 64 + hi4 * 16) ^ ((l15 & 7) << 4);
            *(f32x4*)(ep + l15 * 256 + off) = acc[mf][nf];
        }
        // gather: lane(l15,hi4) reads co-chunk l15 of pixel t*4+hi4
#pragma unroll
        for (int t = 0; t < 4; ++t) {
            const int px = t * 4 + hi4;
            f32x4 vv4 = *(const f32x4*)(ep + px * 256 + ((l15 << 4) ^ ((px & 7) << 4)));
            *(f32x4*)(out + (rowoff + px) * 64 + l15 * 4) = vv4;
        }
    }
}

// ---------------------------------------------------------------------------
extern "C" void kernel_launch(void* const* d_in, const int* in_sizes, int n_in,
                              void* d_out, int out_size, void* d_ws, size_t ws_size,
                              hipStream_t stream)
{
    const float* x      = (const float*)d_in[0];
    const float* conv_w = (const float*)d_in[1];
    const float* qkv_w  = (const float*)d_in[2];
    const float* qkv_b  = (const float*)d_in[3];
    const float* proj_w = (const float*)d_in[4];
    const float* proj_b = (const float*)d_in[5];
    const float* se_w1  = (const float*)d_in[6];
    const float* se_b1  = (const float*)d_in[7];
    const float* se_w2  = (const float*)d_in[8];
    const float* se_b2  = (const float*)d_in[9];
    float* out = (float*)d_out;

    float* qv = (float*)d_ws;            // 147456 f
    float* kv = qv + 147456;             // 147456 f
    float* vv = kv + 147456;             // 147456 f
    float* ao = vv + 147456;             // 147456 f
    ushort* kb = (ushort*)(ao + 147456); // 147456 u16  (total ~2.6 MB)

    hipLaunchKernelGGL(qkv_kernel, dim3(2304), dim3(192), 0, stream,
                       conv_w, qkv_w, qkv_b, qv, kv, vv);
    hipLaunchKernelGGL(attn_kernel, dim3(512), dim3(64), 0, stream, qv, kv, vv, ao);
    hipLaunchKernelGGL(proj_se_kernel, dim3(256), dim3(64), 0, stream,
                       ao, proj_w, proj_b, se_w1, se_b1, se_w2, se_b2, kb);
    hipLaunchKernelGGL(conv_kernel, dim3(2048), dim3(256), 0, stream, x, kb, out);
}

// Round 19
// 83.355 us; speedup vs baseline: 1.0468x; 1.0468x over previous
//
#include <hip/hip_runtime.h>
#include <hip/hip_bf16.h>

typedef __bf16 bf16x8 __attribute__((ext_vector_type(8)));
typedef float  f32x4  __attribute__((ext_vector_type(4)));

// ---------------------------------------------------------------------------
// Stage 1: qkv = kern_tok @ qkv_w + qkv_b ; split into q(scaled),k,v
// (separate small kernels: R15 proved fusing them into 64 blocks costs
// ~39 us; they are ~free under launch overhead at 2304/512/256 blocks.)
// ---------------------------------------------------------------------------
__global__ __launch_bounds__(192) void qkv_kernel(
    const float* __restrict__ conv_w, const float* __restrict__ qkv_w,
    const float* __restrict__ qkv_b,
    float* __restrict__ qv, float* __restrict__ kvv, float* __restrict__ vv)
{
    __shared__ float tok[64];
    const int bid = blockIdx.x;          // co*36 + s
    const int co = bid / 36, s = bid - co * 36;
    const int w = s / 9, p = s - w * 9;
    const int t = threadIdx.x;           // 192
    if (t < 64) tok[t] = conv_w[(((w * 64 + co) * 64 + t) * 9) + p];
    __syncthreads();
    float acc = qkv_b[t];
#pragma unroll 8
    for (int ci = 0; ci < 64; ++ci) acc += tok[ci] * qkv_w[ci * 192 + t];
    const int trip = t >> 6, rem = t & 63, h = rem >> 3, d = rem & 7;
    if (trip == 0) acc *= 0.35355339059327373f;   // hd^-0.5, hd=8
    float* dst = (trip == 0) ? qv : ((trip == 1) ? kvv : vv);
    dst[((co * 8 + h) * 36 + s) * 8 + d] = acc;
}

// ---------------------------------------------------------------------------
// Stage 2: attention per (co, head): softmax(q k^T) v  -> ao[co][s][h*8+d]
// ---------------------------------------------------------------------------
__global__ __launch_bounds__(64) void attn_kernel(
    const float* __restrict__ qv, const float* __restrict__ kvv,
    const float* __restrict__ vv, float* __restrict__ ao)
{
    __shared__ float kl[288], vl[288];
    const int bid = blockIdx.x;          // co*8 + h
    const int t = threadIdx.x;           // 64
    const float* kb = kvv + bid * 288;
    const float* vb = vv + bid * 288;
    for (int i = t; i < 288; i += 64) { kl[i] = kb[i]; vl[i] = vb[i]; }
    __syncthreads();
    if (t < 36) {
        float q[8];
        const float* qb = qv + bid * 288 + t * 8;
#pragma unroll
        for (int d = 0; d < 8; ++d) q[d] = qb[d];
        float sc[36];
        float mx = -1e30f;
#pragma unroll
        for (int u = 0; u < 36; ++u) {
            float a = 0.f;
#pragma unroll
            for (int d = 0; d < 8; ++d) a += q[d] * kl[u * 8 + d];
            sc[u] = a;
            mx = fmaxf(mx, a);
        }
        float sum = 0.f;
        float o[8] = {0.f,0.f,0.f,0.f,0.f,0.f,0.f,0.f};
#pragma unroll
        for (int u = 0; u < 36; ++u) {
            float e = expf(sc[u] - mx);
            sum += e;
#pragma unroll
            for (int d = 0; d < 8; ++d) o[d] += e * vl[u * 8 + d];
        }
        const float inv = 1.0f / sum;
        const int co = bid >> 3, h = bid & 7;
        float* dst = ao + (co * 36 + t) * 64 + h * 8;
#pragma unroll
        for (int d = 0; d < 8; ++d) dst[d] = o[d] * inv;
    }
}

// ---------------------------------------------------------------------------
// Stage 3: proj + SE + write bf16 kernels.
// kout layout: [((h*4 + w)*9 + p)][co][ci32]  (4 KB chunks = one
// (tap, ci-half); conv stages exactly one chunk per pipeline stage).
// ---------------------------------------------------------------------------
__global__ __launch_bounds__(64) void proj_se_kernel(
    const float* __restrict__ ao, const float* __restrict__ proj_w,
    const float* __restrict__ proj_b,
    const float* __restrict__ se_w1, const float* __restrict__ se_b1,
    const float* __restrict__ se_w2, const float* __restrict__ se_b2,
    ushort* __restrict__ kout)
{
    __shared__ float al[9][64];
    __shared__ float pool[64];
    __shared__ float hb[4];
    const int bid = blockIdx.x;          // w*64 + co
    const int w = bid >> 6, co = bid & 63;
    const int t = threadIdx.x;           // 64 (= ci)
    for (int i = t; i < 576; i += 64) {
        int p = i >> 6, j = i & 63;
        al[p][j] = ao[(co * 36 + w * 9 + p) * 64 + j];
    }
    __syncthreads();
    float kv[9];
#pragma unroll
    for (int p = 0; p < 9; ++p) {
        float a = proj_b[t];
#pragma unroll 8
        for (int j = 0; j < 64; ++j) a += al[p][j] * proj_w[j * 64 + t];
        kv[p] = a;
    }
    float pl = 0.f;
#pragma unroll
    for (int p = 0; p < 9; ++p) pl += kv[p];
    pool[t] = pl * (1.0f / 9.0f);
    __syncthreads();
    if (t < 4) {
        float hh = se_b1[w * 4 + t];
#pragma unroll 8
        for (int c = 0; c < 64; ++c) hh += pool[c] * se_w1[(w * 4 + t) * 64 + c];
        hb[t] = fmaxf(hh, 0.0f);
    }
    __syncthreads();
    float z = se_b2[w * 64 + t];
#pragma unroll
    for (int d = 0; d < 4; ++d) z += hb[d] * se_w2[(w * 64 + t) * 4 + d];
    const float sg = 1.0f / (1.0f + expf(-z));
    const int hhalf = t >> 5, ci32 = t & 31;
#pragma unroll
    for (int p = 0; p < 9; ++p) {
        __hip_bfloat16 hv = __float2bfloat16(kv[p] * sg);
        kout[(((hhalf * 4 + w) * 9) + p) * 2048 + co * 32 + ci32] = *(const ushort*)&hv;
    }
}

// ---------------------------------------------------------------------------
// Stage 4: dynamic per-window 3x3 conv, implicit GEMM, bf16 MFMA.
// R13 VERBATIM -- the session's verified optimum (83.4 / 84.2 us e2e,
// measured twice). Plateau evidence (13 structural variants bracketed):
// bytes ideal (WRITE exactly 131072 KB, FETCH 66 MB LLC-absorbed),
// conflicts 0, no spill; occupancy-insensitive both ways (R14: 4 blk/CU
// 16x8 tile -> 85.8; R18: 9 K=64 stages 2 blk/CU -> 87.3); kern-in-regs
// blocked by compiler load-sinking / asm fragility (R7/R8/R9); (256,4) =
// structural spill wall (R10/R11); staging-weave negative (R12);
// small-kernel fusion negative (R15). Counted-vmcnt kern triple-buffer
// via global_load_lds (linear dest + pre-swizzled global source),
// vmcnt(1) mid-loop / vmcnt(0) at s=17, issue s+2 right after the
// barrier, full-channel in_lds with 0-conflict col-XOR swizzle, deep
// 21-load prologue staging, LDS-transpose epilogue with plain cached
// 1 KB-contiguous stores. LDS 53760 B -> 3 blocks/CU.
// ---------------------------------------------------------------------------
__global__ __launch_bounds__(256, 3) void conv_kernel(
    const float* __restrict__ x, const ushort* __restrict__ kern,
    float* __restrict__ out)
{
    __shared__ alignas(16) ushort in_lds[18 * 18 * 64];   // 41472 B
    __shared__ alignas(16) ushort kn_lds[3 * 2048];       // 12288 B (3 x 4KB)

    const int tid = threadIdx.x;

    // ---- XCD-chunked bijective remap: XCD k processes nb in [k*256,(k+1)*256)
    const int bid = blockIdx.x;                 // 0..2047, xcd = bid & 7
    const int nb  = ((bid & 7) << 8) + (bid >> 3);
    const int bz  = nb >> 6;                    // (w*8+b), 4 per XCD
    const int rem = nb & 63;
    const int i0  = (rem >> 3) << 4;
    const int j0  = (rem & 7) << 4;
    const int w = bz >> 3, b = bz & 7;
    const int gi = w >> 1, gj = w & 1;

    const int wv   = tid >> 6;
    const int lane = tid & 63;
    const int l15  = lane & 15;
    const int hi4  = lane >> 4;        // 0..3

    // ---- async kern stage: stage s = (p = s>>1, half = s&1) -> one 4 KB
    // chunk at kern + (((half*4+w)*9)+p)*4096. Linear LDS dest; read-side
    // swizzle realized by pre-swizzling the GLOBAL source (both-sides rule).
    const char* kern_b = (const char*)kern;
    const int ksrc = (lane << 4) ^ (((lane >> 3) & 3) << 4);
    auto stage_kern = [&](int s, int buf) {
        const int p = s >> 1, hh = s & 1;
        const char* gs = kern_b + ((size_t)((((hh * 4 + w) * 9)) + p) << 12);
        __builtin_amdgcn_global_load_lds(
            (const __attribute__((address_space(1))) unsigned int*)(gs + (wv << 10) + ksrc),
            (__attribute__((address_space(3))) unsigned int*)
                ((char*)kn_lds + (buf << 12) + (wv << 10)),
            16, 0, 0);
    };

    // ---- prologue: issue kern stages 0,1 first (they fly under the input
    // staging burst), then stage the FULL input tile, then ONE full drain.
    stage_kern(0, 0);
    stage_kern(1, 1);

    // input staging, FULL 64 channels: 18x18 px * 128 B, 16 thr/px (4 ch).
    // All 21 clamped loads issued before the cvt/write pass (deep flight).
    // LDS position: (pp<<7) + ((cc*2) ^ ((q&7)<<4))  [0-conflict swizzle]
    {
        const int cc = (tid & 15) << 2;    // channel 0..60
        const int p0 = tid >> 4;           // 0..15
        float4 v[21];
        unsigned okm = 0;
#pragma unroll
        for (int k = 0; k < 21; ++k) {
            const int pp = p0 + (k << 4);          // <= 335
            const int ppc = pp < 323 ? pp : 323;
            const int r = ppc / 18, q = ppc - r * 18;
            const int iy = i0 - 1 + r, jx = j0 - 1 + q;
            const bool ok = (pp < 324) & (iy >= 0) & (iy < 128) & (jx >= 0) & (jx < 128);
            const int iyc = iy < 0 ? 0 : (iy > 127 ? 127 : iy);
            const int jxc = jx < 0 ? 0 : (jx > 127 ? 127 : jx);
            const size_t xi = (((size_t)b << 16) +
                               (size_t)(gi * 128 + iyc) * 256 + (size_t)(gj * 128 + jxc)) * 64 + cc;
            v[k] = *(const float4*)(x + xi);
            okm |= (unsigned)ok << k;
        }
#pragma unroll
        for (int k = 0; k < 21; ++k) {
            const int pp = p0 + (k << 4);
            if (pp < 324) {
                const int r = pp / 18, q = pp - r * 18;
                float4 z = (okm >> k) & 1 ? v[k] : make_float4(0.f, 0.f, 0.f, 0.f);
                union { ushort4 u; ushort h4[4]; } tmp;
                __hip_bfloat16 b0 = __float2bfloat16(z.x); tmp.h4[0] = *(const ushort*)&b0;
                __hip_bfloat16 b1 = __float2bfloat16(z.y); tmp.h4[1] = *(const ushort*)&b1;
                __hip_bfloat16 b2 = __float2bfloat16(z.z); tmp.h4[2] = *(const ushort*)&b2;
                __hip_bfloat16 b3 = __float2bfloat16(z.w); tmp.h4[3] = *(const ushort*)&b3;
                *(ushort4*)((char*)in_lds +
                    ((pp << 7) + ((cc << 1) ^ ((q & 7) << 4)))) = tmp.u;
            }
        }
    }

    f32x4 acc[4][4];
#pragma unroll
    for (int mf = 0; mf < 4; ++mf)
#pragma unroll
        for (int nf = 0; nf < 4; ++nf)
            acc[mf][nf] = (f32x4){0.f, 0.f, 0.f, 0.f};

    __syncthreads();     // the ONE full drain: input ds_writes + kern 0,1

#pragma unroll
    for (int s = 0; s < 18; ++s) {
        // counted wait: set s retired when <=1 outstanding ({s, s+1} in
        // flight at stage top). s=17: queue is {17} alone -> vmcnt(0).
        if (s < 17) asm volatile("s_waitcnt vmcnt(1)" ::: "memory");
        else        asm volatile("s_waitcnt vmcnt(0)" ::: "memory");
        __builtin_amdgcn_sched_barrier(0);
        __builtin_amdgcn_s_barrier();      // all waves' set-s loads in LDS
        __builtin_amdgcn_sched_barrier(0);

        // issue load(s+2) into buf[(s+2)%3] before compute: all waves past
        // this barrier => all finished compute(s-1) = last readers of it.
        if (s < 16) stage_kern(s + 2, (s + 2) % 3);

        const int buf = s % 3;
        const int p = s >> 1, hh = s & 1;
        const int kh = p / 3, kw = p - kh * 3;

        // kern fragments: co = nf*16+l15, ci-chunk hi4 within this half
        bf16x8 Kf[4];
#pragma unroll
        for (int nf = 0; nf < 4; ++nf) {
            const int co = nf * 16 + l15;
            Kf[nf] = *(const bf16x8*)((const char*)kn_lds +
                      ((buf << 12) + (co << 6) +
                       ((hi4 << 4) ^ (((co >> 1) & 3) << 4))));
        }

        const int q = l15 + kw;
        const int swz = (q & 7) << 4;
        const int c2 = (hh << 6) | (hi4 << 4);
#pragma unroll
        for (int mf = 0; mf < 4; ++mf) {
            const int r = wv * 4 + mf + kh;
            bf16x8 Af = *(const bf16x8*)((const char*)in_lds +
                          (((r * 18 + q) << 7) + (c2 ^ swz)));
#pragma unroll
            for (int nf = 0; nf < 4; ++nf)
                acc[mf][nf] = __builtin_amdgcn_mfma_f32_16x16x32_bf16(
                    Kf[nf], Af, acc[mf][nf], 0, 0, 0);
        }
    }

    // ---- pre-epilogue barrier: my ds_reads retired (lgkm 0), then all
    // waves arrive => nobody still reads in_lds when we overwrite it.
    asm volatile("s_waitcnt lgkmcnt(0)" ::: "memory");
    __builtin_amdgcn_sched_barrier(0);
    __builtin_amdgcn_s_barrier();
    __builtin_amdgcn_sched_barrier(0);

    // ---- LDS-transpose epilogue (wave-private 4 KB region). Plain cached
    // stores, 1 KB contiguous per wave-instruction.
    char* ep = (char*)in_lds + (wv << 12);
#pragma unroll
    for (int mf = 0; mf < 4; ++mf) {
        const int iloc = wv * 4 + mf;
        const size_t rowoff = ((size_t)b << 16) +
                              (size_t)(gi * 128 + i0 + iloc) * 256 + (size_t)(gj * 128 + j0);
        // scatter: lane(l15,hi4) holds co = nf*16+hi4*4+reg at pixel l15
#pragma unroll
        for (int nf = 0; nf < 4; ++nf) {
            const int off = (nf * 64 + hi4 * 16) ^ ((l15 & 7) << 4);
            *(f32x4*)(ep + l15 * 256 + off) = acc[mf][nf];
        }
        // gather: lane(l15,hi4) reads co-chunk l15 of pixel t*4+hi4
#pragma unroll
        for (int t = 0; t < 4; ++t) {
            const int px = t * 4 + hi4;
            f32x4 vv4 = *(const f32x4*)(ep + px * 256 + ((l15 << 4) ^ ((px & 7) << 4)));
            *(f32x4*)(out + (rowoff + px) * 64 + l15 * 4) = vv4;
        }
    }
}

// ---------------------------------------------------------------------------
extern "C" void kernel_launch(void* const* d_in, const int* in_sizes, int n_in,
                              void* d_out, int out_size, void* d_ws, size_t ws_size,
                              hipStream_t stream)
{
    const float* x      = (const float*)d_in[0];
    const float* conv_w = (const float*)d_in[1];
    const float* qkv_w  = (const float*)d_in[2];
    const float* qkv_b  = (const float*)d_in[3];
    const float* proj_w = (const float*)d_in[4];
    const float* proj_b = (const float*)d_in[5];
    const float* se_w1  = (const float*)d_in[6];
    const float* se_b1  = (const float*)d_in[7];
    const float* se_w2  = (const float*)d_in[8];
    const float* se_b2  = (const float*)d_in[9];
    float* out = (float*)d_out;

    float* qv = (float*)d_ws;            // 147456 f
    float* kv = qv + 147456;             // 147456 f
    float* vv = kv + 147456;             // 147456 f
    float* ao = vv + 147456;             // 147456 f
    ushort* kb = (ushort*)(ao + 147456); // 147456 u16  (total ~2.6 MB)

    hipLaunchKernelGGL(qkv_kernel, dim3(2304), dim3(192), 0, stream,
                       conv_w, qkv_w, qkv_b, qv, kv, vv);
    hipLaunchKernelGGL(attn_kernel, dim3(512), dim3(64), 0, stream, qv, kv, vv, ao);
    hipLaunchKernelGGL(proj_se_kernel, dim3(256), dim3(64), 0, stream,
                       ao, proj_w, proj_b, se_w1, se_b1, se_w2, se_b2, kb);
    hipLaunchKernelGGL(conv_kernel, dim3(2048), dim3(256), 0, stream, x, kb, out);
}